// Round 16
// baseline (5274.423 us; speedup 1.0000x reference)
//
#include <hip/hip_runtime.h>

// DecoderRNN: 3-layer LSTM (H=1024) + fc, B=256, 128 steps, constant input.
// bf16 MFMA 16x16x32; gate-interleaved weight columns; persistent plain-launch
// kernel; h-state via device-coherent loads; leader-only release fence
// (R15-proven: 8 wbl2/step instead of 392).
// THIS ROUND: tile 64(M) x 256(N) (4 gate groups/block) -> 64 blocks/job,
// A(h) fabric traffic 160 -> 40 MB/step (total ~100 MB/step, -60%).
// Grid 196; 8 waves = 2(M) x 4(N-group); wave = 32x64 (R8's proven shape).

#define DEVINL static __device__ __forceinline__

typedef __bf16 bf16x8 __attribute__((ext_vector_type(8)));
typedef float f32x4 __attribute__((ext_vector_type(4)));
typedef unsigned short u16;
typedef unsigned int u32;
typedef unsigned long long u64;

DEVINL u16 f2bf(float f) {
  u32 u = __builtin_bit_cast(u32, f);
  u += 0x7fffu + ((u >> 16) & 1u);  // RNE
  return (u16)(u >> 16);
}
DEVINL float bf2f(u16 h) {
  u32 u = (u32)h << 16;
  return __builtin_bit_cast(float, u);
}
DEVINL float sigm(float x) { return 1.0f / (1.0f + __expf(-x)); }
DEVINL float tanhfast(float x) { return 1.0f - 2.0f / (1.0f + __expf(2.0f * x)); }

// device-coherent global->LDS (h-state: written by other XCDs) [R8-proven]
DEVINL void glds_coh(const u16* g, u16* l) {
  __builtin_amdgcn_global_load_lds(
      (const __attribute__((address_space(1))) u32*)g,
      (__attribute__((address_space(3))) u32*)l, 16, 0, 17);  // sc0|sc1
}
// cached global->LDS (weights: read-only)
DEVINL void glds_w(const u16* g, u16* l) {
  __builtin_amdgcn_global_load_lds(
      (const __attribute__((address_space(1))) u32*)g,
      (__attribute__((address_space(3))) u32*)l, 16, 0, 0);
}

// permuted column index -> original gate column: P = grp*64 + g*16 + jj
DEVINL int permcol(int P) {
  int grp = P >> 6, g = (P >> 4) & 3, jj = P & 15;
  return g * 1024 + grp * 16 + jj;
}

struct Params {
  const float* fc_b;
  const float* inh_b;
  const float* inc_b;
  const u16 *WT0, *WT1, *WT2, *WT00, *FCW, *WIH, *WIC, *FRB;
  u16* HB;   // h state bf16: [layer][parity][256][1024]  (1<<18 u16 per buf)
  u16* G0P;  // precomputed layer0 input gates, bf16 [256][4096]
  float *G0B, *B1P, *B2P, *CC;  // CC: c state fp32 [layer][256][1024]
  float* out;
};

#define MODE_L0 0
#define MODE_L 1
#define MODE_FC 2
#define MODE_G0 3
#define MODE_H 4
#define MODE_C 5

#define ASLOT 4096   // u16 per A slot (64 rows x 64 k)
#define BSLOT 16384  // u16 per B slot (256 rows x 64 k)

// one 64-K tile: per thread 1 A-load (coherent) + 4 B-loads (cached),
// direct to LDS. Source-side XOR swizzle (granule ^ row&7); LDS dest linear.
DEVINL void issue_tile(int kt, const u16* A0, const u16* A1, int kSplit, int sA,
                       int K, const u16* Wt, int m0, int wrow, int rqA, int kqA,
                       int loA, const int (&rqB)[4], const int (&kqB)[4],
                       const int (&loB)[4], u16* Abuf, u16* Bbuf) {
  const u16* Ab = (kt < kSplit) ? (A0 + kt) : (A1 + (kt - kSplit));
  glds_coh(Ab + (size_t)(m0 + rqA) * sA + kqA * 8, Abuf + loA);
  const u16* Bb = Wt + kt;
#pragma unroll
  for (int q = 0; q < 4; ++q)
    glds_w(Bb + (size_t)(wrow + rqB[q]) * K + kqB[q] * 8, Bbuf + loB[q]);
}

// wave computes 32(M) x 64(N): 2 M-frags x 4 N-frags, K=64 per tile
DEVINL void mfma_tile(const u16* Al, const u16* Bl, f32x4 (&acc)[2][4], int rl0,
                      int nb0, int hh, int e7) {
#pragma unroll
  for (int kk = 0; kk < 2; ++kk) {
    int sl = (((kk << 2) | hh) ^ e7) * 8;
    bf16x8 a0 = *(const bf16x8*)(Al + rl0 * 64 + sl);
    bf16x8 a1 = *(const bf16x8*)(Al + (rl0 + 16) * 64 + sl);
    bf16x8 b0 = *(const bf16x8*)(Bl + (nb0)*64 + sl);
    bf16x8 b1 = *(const bf16x8*)(Bl + (nb0 + 16) * 64 + sl);
    bf16x8 b2 = *(const bf16x8*)(Bl + (nb0 + 32) * 64 + sl);
    bf16x8 b3 = *(const bf16x8*)(Bl + (nb0 + 48) * 64 + sl);
    acc[0][0] = __builtin_amdgcn_mfma_f32_16x16x32_bf16(a0, b0, acc[0][0], 0, 0, 0);
    acc[0][1] = __builtin_amdgcn_mfma_f32_16x16x32_bf16(a0, b1, acc[0][1], 0, 0, 0);
    acc[0][2] = __builtin_amdgcn_mfma_f32_16x16x32_bf16(a0, b2, acc[0][2], 0, 0, 0);
    acc[0][3] = __builtin_amdgcn_mfma_f32_16x16x32_bf16(a0, b3, acc[0][3], 0, 0, 0);
    acc[1][0] = __builtin_amdgcn_mfma_f32_16x16x32_bf16(a1, b0, acc[1][0], 0, 0, 0);
    acc[1][1] = __builtin_amdgcn_mfma_f32_16x16x32_bf16(a1, b1, acc[1][1], 0, 0, 0);
    acc[1][2] = __builtin_amdgcn_mfma_f32_16x16x32_bf16(a1, b2, acc[1][2], 0, 0, 0);
    acc[1][3] = __builtin_amdgcn_mfma_f32_16x16x32_bf16(a1, b3, acc[1][3], 0, 0, 0);
  }
}

// Block: 512 threads = 8 waves (2M x 4N-groups), output tile 64(M) x 256(N).
// Wave w: rows m0 + (w&1)*32 + [0,32), permuted cols bn*256 + (w>>1)*64 +
// [0,64) (one full gate group per wave -> lane-local cell update).
// LDS double-buffered; counted vmcnt(5): next tile's 5 loads stay in flight.
template <int MODE>
DEVINL void mm_body(u16* Al, u16* Bl, const u16* A0, const u16* A1, int sA,
                    int kSplit, int K, const u16* Wt, int m0, int bn, int t,
                    const u16* Gfull, const float* biasP, float* Cst, u16* Hout,
                    float* outp) {
  const int tid = threadIdx.x;
  const int l = tid & 63;
  const int w = tid >> 6;  // 0..7
  const int hh = (l >> 4) & 3;
  const int jj = l & 15;
  const int rl0 = (w & 1) * 32 + jj;   // A row of m-frag 0 (rl0&7 == l&7)
  const int nb0 = (w >> 1) * 64 + jj;  // B-tile row of n-frag 0
  const int e7 = l & 7;

  const int rqA = tid >> 3;               // 0..63
  const int kqA = (tid & 7) ^ (rqA & 7);  // source-swizzled granule
  const int loA = (tid & ~63) * 8;        // wave-uniform LDS base (u16)
  int rqB[4], kqB[4], loB[4];
#pragma unroll
  for (int q = 0; q < 4; ++q) {
    int L = tid + q * 512;
    rqB[q] = L >> 3;  // 0..255
    kqB[q] = (L & 7) ^ (rqB[q] & 7);
    loB[q] = ((tid & ~63) + q * 512) * 8;
  }

  f32x4 acc[2][4];
#pragma unroll
  for (int m = 0; m < 2; ++m)
#pragma unroll
    for (int g = 0; g < 4; ++g) acc[m][g] = (f32x4){0.f, 0.f, 0.f, 0.f};

  const int wrow = bn * 256;
  const int nt = K >> 6;  // 64-K tiles; nt in {4,16,32}

  issue_tile(0, A0, A1, kSplit, sA, K, Wt, m0, wrow, rqA, kqA, loA, rqB, kqB,
             loB, Al, Bl);
  issue_tile(64, A0, A1, kSplit, sA, K, Wt, m0, wrow, rqA, kqA, loA, rqB, kqB,
             loB, Al + ASLOT, Bl + BSLOT);

  for (int j = 0; j < nt; ++j) {
    u16* Ac = Al + (j & 1) * ASLOT;
    u16* Bc = Bl + (j & 1) * BSLOT;
    if (j < nt - 1)
      asm volatile("s_waitcnt vmcnt(5)" ::: "memory");
    else
      asm volatile("s_waitcnt vmcnt(0)" ::: "memory");
    __builtin_amdgcn_s_barrier();
    __builtin_amdgcn_sched_barrier(0);
    mfma_tile(Ac, Bc, acc, rl0, nb0, hh, e7);
    __builtin_amdgcn_sched_barrier(0);
    __builtin_amdgcn_s_barrier();
    if (j + 2 < nt)
      issue_tile((j + 2) * 64, A0, A1, kSplit, sA, K, Wt, m0, wrow, rqA, kqA,
                 loA, rqB, kqB, loB, Ac, Bc);
  }

  // C/D layout: col = lane&15, row = (lane>>4)*4 + reg  [m89-verified]
  const int rb = m0 + (w & 1) * 32 + (hh << 2);
  const int nb = bn * 256 + (w >> 1) * 64;  // permuted col base (gate group)
  if (MODE <= MODE_L) {
    float add0 = 0.f, add1 = 0.f, add2 = 0.f, add3 = 0.f;
    if (MODE == MODE_L) {
      add0 = biasP[nb + jj];
      add1 = biasP[nb + 16 + jj];
      add2 = biasP[nb + 32 + jj];
      add3 = biasP[nb + 48 + jj];
    }
    const int j = (nb >> 6) * 16 + jj;  // hidden unit
#pragma unroll
    for (int m = 0; m < 2; ++m) {
#pragma unroll
      for (int r = 0; r < 4; ++r) {
        int b = rb + m * 16 + r;
        float g0v, g1v, g2v, g3v;
        if (MODE == MODE_L0) {
          const u16* G = Gfull + (size_t)b * 4096 + nb + jj;
          g0v = acc[m][0][r] + bf2f(G[0]);
          g1v = acc[m][1][r] + bf2f(G[16]);
          g2v = acc[m][2][r] + bf2f(G[32]);
          g3v = acc[m][3][r] + bf2f(G[48]);
        } else {
          g0v = acc[m][0][r] + add0;
          g1v = acc[m][1][r] + add1;
          g2v = acc[m][2][r] + add2;
          g3v = acc[m][3][r] + add3;
        }
        float iv = sigm(g0v), fv = sigm(g1v), gv = tanhfast(g2v), ov = sigm(g3v);
        size_t ci = (size_t)b * 1024 + j;
        float cn = fv * Cst[ci] + iv * gv;
        Cst[ci] = cn;
        Hout[ci] = f2bf(ov * tanhfast(cn));
      }
    }
  } else if (MODE == MODE_FC) {
#pragma unroll
    for (int g = 0; g < 4; ++g) {
      int nn = nb + g * 16 + jj;
      if (nn < 204) {
        float bv2 = biasP[nn];
#pragma unroll
        for (int m = 0; m < 2; ++m)
#pragma unroll
          for (int r = 0; r < 4; ++r) {
            int b = rb + m * 16 + r;
            outp[((size_t)b * 128 + t) * 204 + nn] = acc[m][g][r] + bv2;
          }
      }
    }
  } else if (MODE == MODE_G0) {
#pragma unroll
    for (int g = 0; g < 4; ++g) {
      int P = nb + g * 16 + jj;
      float bv2 = biasP[P];
#pragma unroll
      for (int m = 0; m < 2; ++m)
#pragma unroll
        for (int r = 0; r < 4; ++r) {
          int b = rb + m * 16 + r;
          Hout[(size_t)b * 4096 + P] = f2bf(acc[m][g][r] + bv2);
        }
    }
  } else {  // MODE_H / MODE_C : init states, cols are orig n = lay*1024 + j
#pragma unroll
    for (int g = 0; g < 4; ++g) {
      int nn = nb + g * 16 + jj;
      int lay = nn >> 10, j2 = nn & 1023;
      float bv2 = biasP[nn];
#pragma unroll
      for (int m = 0; m < 2; ++m)
#pragma unroll
        for (int r = 0; r < 4; ++r) {
          int b = rb + m * 16 + r;
          float v = acc[m][g][r] + bv2;
          if (MODE == MODE_H)
            Hout[(size_t)((lay * 2 + 1) * 256 + b) * 1024 + j2] = f2bf(v);
          else
            outp[(size_t)(lay * 256 + b) * 1024 + j2] = v;
        }
    }
  }
}

// BAR layout (u32 idx): per-XCD global arrive x*64 (x<8); flag @512;
// census one-shot counter @768; census counts @1024+x*64; per-XCD step
// counters @2048+x*64.  (16 KB total, memset to 0 each call.)

// Step barrier with leader-only release fence (R15-proven).
DEVINL void step_barrier(u32* bar, int bid, int x, int rank, int nb, int ep) {
  __syncthreads();  // drains this block's stores into L2
  const int tid = threadIdx.x;
  if (tid == 0) {
    __hip_atomic_fetch_add(bar + 2048 + x * 64, 1u, __ATOMIC_RELAXED,
                           __HIP_MEMORY_SCOPE_AGENT);
    if (rank == 0) {
#pragma unroll 1
      while (__hip_atomic_load(bar + 2048 + x * 64, __ATOMIC_RELAXED,
                               __HIP_MEMORY_SCOPE_AGENT) < (u32)ep * (u32)nb)
        __builtin_amdgcn_s_sleep(4);
      __builtin_amdgcn_fence(__ATOMIC_RELEASE, "agent");  // 1 wbl2 / XCD
      __hip_atomic_fetch_add(bar + x * 64, 1u, __ATOMIC_RELAXED,
                             __HIP_MEMORY_SCOPE_AGENT);
    }
  }
  if (bid == 0) {
    if (tid < 8) {
      u32 cnt = __hip_atomic_load(bar + 1024 + tid * 64, __ATOMIC_RELAXED,
                                  __HIP_MEMORY_SCOPE_AGENT);
      if (cnt > 0) {
#pragma unroll 1
        while (__hip_atomic_load(bar + tid * 64, __ATOMIC_RELAXED,
                                 __HIP_MEMORY_SCOPE_AGENT) < (u32)ep)
          __builtin_amdgcn_s_sleep(4);
      }
    }
    __syncthreads();  // all 8 poll lanes done
    if (tid == 0)
      __hip_atomic_store(bar + 512, (u32)ep, __ATOMIC_RELAXED,
                         __HIP_MEMORY_SCOPE_AGENT);
  } else if (tid == 0) {
#pragma unroll 1
    while (__hip_atomic_load(bar + 512, __ATOMIC_RELAXED,
                             __HIP_MEMORY_SCOPE_AGENT) < (u32)ep)
      __builtin_amdgcn_s_sleep(8);
  }
  __syncthreads();
}

// Persistent pipelined kernel, PLAIN launch; 196 blocks <= 256 CUs, 80KB LDS
// -> all co-resident, software barrier safe.
// jobs 0..2: 64 blocks each (16 bn-stripes of 256 cols x 4 M-quarters);
// fc: 4 (bn=0). bid&7 ~ XCD affinity (bn>>1 == bid&7 for layer jobs).
__global__ __launch_bounds__(512, 2) void persist_kernel(Params p, u32* bar) {
  __shared__ u16 Al[2 * ASLOT];  // 16KB
  __shared__ u16 Bl[2 * BSLOT];  // 64KB
  __shared__ int sh_x, sh_rank, sh_nb;
  const int bid = blockIdx.x;
  int job, mb, bn;
  if (bid < 192) {
    job = bid >> 6;
    int r = bid & 63;
    bn = (r & 7) * 2 + (r >> 5);  // 0..15; bn>>1 == bid&7 (XCD-affine)
    mb = (r >> 3) & 3;            // M-quarter (64 rows)
  } else {
    job = 3;
    mb = bid - 192;  // 0..3
    bn = 0;
  }

  // ---- XCD census (R9/R15-proven: physical XCD id + per-XCD rank) ----
  if (threadIdx.x == 0) {
    int x = __builtin_amdgcn_s_getreg((31 << 11) | 20) & 7;  // HW_REG_XCC_ID
    sh_x = x;
    sh_rank = (int)__hip_atomic_fetch_add(bar + 1024 + x * 64, 1u,
                                          __ATOMIC_RELAXED,
                                          __HIP_MEMORY_SCOPE_AGENT);
  }
  __syncthreads();
  const int x = sh_x, rank = sh_rank;
  if (threadIdx.x == 0) {  // census complete barrier (one-shot, 196 arrivals)
    __hip_atomic_fetch_add(bar + 768, 1u, __ATOMIC_RELAXED,
                           __HIP_MEMORY_SCOPE_AGENT);
#pragma unroll 1
    while (__hip_atomic_load(bar + 768, __ATOMIC_RELAXED,
                             __HIP_MEMORY_SCOPE_AGENT) < 196u)
      __builtin_amdgcn_s_sleep(8);
    sh_nb = (int)__hip_atomic_load(bar + 1024 + x * 64, __ATOMIC_RELAXED,
                                   __HIP_MEMORY_SCOPE_AGENT);
  }
  __syncthreads();
  const int nb = sh_nb;

  u16* HB = p.HB;
#define HBP(lay, pp) (HB + (size_t)(((lay)*2 + (pp)) << 18))
  for (int i = 0; i <= 130; ++i) {
    int t = i - job;
    if ((unsigned)t < 128u) {
      int par = t & 1, pv = par ^ 1;
      if (job == 0) {
        mm_body<MODE_L0>(Al, Bl, HBP(0, pv), nullptr, 1024, 1 << 30, 1024,
                         p.WT0, mb * 64, bn, t, p.G0P, nullptr, p.CC,
                         HBP(0, par), nullptr);
      } else if (job == 1) {
        mm_body<MODE_L>(Al, Bl, HBP(0, par), HBP(1, pv), 1024, 1024, 2048,
                        p.WT1, mb * 64, bn, t, nullptr, p.B1P,
                        p.CC + (size_t)256 * 1024, HBP(1, par), nullptr);
      } else if (job == 2) {
        mm_body<MODE_L>(Al, Bl, HBP(1, par), HBP(2, pv), 1024, 1024, 2048,
                        p.WT2, mb * 64, bn, t, nullptr, p.B2P,
                        p.CC + (size_t)512 * 1024, HBP(2, par), nullptr);
      } else {
        mm_body<MODE_FC>(Al, Bl, HBP(2, par), nullptr, 1024, 1 << 30, 1024,
                         p.FCW, mb * 64, bn, t, nullptr, p.fc_b, nullptr,
                         nullptr, p.out);
      }
    }
    if (i < 130) step_barrier(bar, bid, x, rank, nb, i + 1);
  }
#undef HBP
}

// one-time: G0 = x_in@W_ih0+biases (permuted), h/c init = frame@in{h,c}_W + b
// 160 blocks: G0 64 (4 mb x 16 bn), H 48 (4 mb x 12 bn), C 48.
__global__ __launch_bounds__(512, 2) void setup_mm(Params p) {
  __shared__ u16 Al[2 * ASLOT];
  __shared__ u16 Bl[2 * BSLOT];
  int bid = blockIdx.x;
  if (bid < 64) {
    mm_body<MODE_G0>(Al, Bl, p.FRB, nullptr, 256, 1 << 30, 256, p.WT00,
                     (bid >> 4) * 64, bid & 15, 0, nullptr, p.G0B, nullptr,
                     p.G0P, nullptr);
  } else if (bid < 112) {
    int r = bid - 64;
    mm_body<MODE_H>(Al, Bl, p.FRB, nullptr, 256, 1 << 30, 256, p.WIH,
                    (r / 12) * 64, r % 12, 0, nullptr, p.inh_b, nullptr, p.HB,
                    nullptr);
  } else {
    int r = bid - 112;
    mm_body<MODE_C>(Al, Bl, p.FRB, nullptr, 256, 1 << 30, 256, p.WIC,
                    (r / 12) * 64, r % 12, 0, nullptr, p.inc_b, nullptr,
                    nullptr, p.CC);
  }
}

// fp32 [K][N] sources -> bf16 transposed dst [Nout][Ktot] (K contiguous),
// optional gate permutation of output cols, zero pad k>=Kvalid / n>=Nvalid.
__global__ __launch_bounds__(256) void transpose_bf16(
    const float* __restrict__ srcA, const float* __restrict__ srcB,
    int srcStride, int kSplit, int Kvalid, int Nvalid, int perm,
    u16* __restrict__ dst, int Ktot) {
  __shared__ float tile[64][17];
  int P0 = blockIdx.x * 16;
  int k0 = blockIdx.y * 64;
  int t = threadIdx.x;
  int nl = t & 15;
  int kh = t >> 4;
  int P = P0 + nl;
  int n = perm ? permcol(P) : P;
  bool nok = (n < Nvalid);
#pragma unroll
  for (int q = 0; q < 4; ++q) {
    int kl = q * 16 + kh;
    int k = k0 + kl;
    float v = 0.f;
    if (nok && k < Kvalid) {
      const float* s = (k < kSplit) ? (srcA + (size_t)k * srcStride)
                                    : (srcB + (size_t)(k - kSplit) * srcStride);
      v = s[n];
    }
    tile[kl][nl] = v;
  }
  __syncthreads();
  int jo = t >> 4;
  int kb = (t & 15) << 2;
  u64 pk = (u64)f2bf(tile[kb + 0][jo]) | ((u64)f2bf(tile[kb + 1][jo]) << 16) |
           ((u64)f2bf(tile[kb + 2][jo]) << 32) |
           ((u64)f2bf(tile[kb + 3][jo]) << 48);
  *(u64*)(dst + (size_t)(P0 + jo) * Ktot + k0 + kb) = pk;
}

__global__ __launch_bounds__(256) void build_frame(const float* __restrict__ inputs,
                                                   u16* __restrict__ FRB) {
  int id = blockIdx.x * 256 + threadIdx.x;  // 256*256
  int b = id >> 8, k = id & 255;
  FRB[id] = (k < 204) ? f2bf(inputs[b * 204 + k]) : (u16)0;
}

// G0 bias incl. one-hot label row; layer1/2 combined biases (permuted cols)
__global__ __launch_bounds__(256) void build_bias(
    const float* __restrict__ W_ih0, const float* __restrict__ b_ih0,
    const float* __restrict__ b_hh0, const float* __restrict__ b_ih1,
    const float* __restrict__ b_hh1, const float* __restrict__ b_ih2,
    const float* __restrict__ b_hh2, const int* __restrict__ labels,
    float* __restrict__ G0B, float* __restrict__ B1P, float* __restrict__ B2P) {
  int P = blockIdx.x * 256 + threadIdx.x;  // 4096
  int n = permcol(P);
  int lab = labels[0];
  G0B[P] = W_ih0[(size_t)(204 + lab) * 4096 + n] + b_ih0[n] + b_hh0[n];
  B1P[P] = b_ih1[n] + b_hh1[n];
  B2P[P] = b_ih2[n] + b_hh2[n];
}

extern "C" void kernel_launch(void* const* d_in, const int* in_sizes, int n_in,
                              void* d_out, int out_size, void* d_ws,
                              size_t ws_size, hipStream_t stream) {
  const float* inputs = (const float*)d_in[0];
  const float* W_ih0 = (const float*)d_in[1];
  const float* W_hh0 = (const float*)d_in[2];
  const float* b_ih0 = (const float*)d_in[3];
  const float* b_hh0 = (const float*)d_in[4];
  const float* W_ih1 = (const float*)d_in[5];
  const float* W_hh1 = (const float*)d_in[6];
  const float* b_ih1 = (const float*)d_in[7];
  const float* b_hh1 = (const float*)d_in[8];
  const float* W_ih2 = (const float*)d_in[9];
  const float* W_hh2 = (const float*)d_in[10];
  const float* b_ih2 = (const float*)d_in[11];
  const float* b_hh2 = (const float*)d_in[12];
  const float* fc_W = (const float*)d_in[13];
  const float* fc_b = (const float*)d_in[14];
  const float* inh_W = (const float*)d_in[15];
  const float* inh_b = (const float*)d_in[16];
  const float* inc_W = (const float*)d_in[17];
  const float* inc_b = (const float*)d_in[18];
  const int* labels = (const int*)d_in[19];

  char* ws = (char*)d_ws;
  size_t off = 0;
  auto alloc = [&](size_t bytes) {
    void* r = ws + off;
    off = (off + bytes + 255) & ~(size_t)255;
    return r;
  };
  u16* WT0 = (u16*)alloc(4096ull * 1024 * 2);
  u16* WT1 = (u16*)alloc(4096ull * 2048 * 2);
  u16* WT2 = (u16*)alloc(4096ull * 2048 * 2);
  u16* WT00 = (u16*)alloc(4096ull * 256 * 2);
  u16* FCW = (u16*)alloc(256ull * 1024 * 2);
  u16* WIH = (u16*)alloc(3072ull * 256 * 2);
  u16* WIC = (u16*)alloc(3072ull * 256 * 2);
  u16* FRB = (u16*)alloc(256ull * 256 * 2);
  u16* HB = (u16*)alloc(3ull * 2 * 256 * 1024 * 2);
  u16* G0P = (u16*)alloc(256ull * 4096 * 2);
  float* G0B = (float*)alloc(4096ull * 4);
  float* B1P = (float*)alloc(4096ull * 4);
  float* B2P = (float*)alloc(4096ull * 4);
  float* CC = (float*)alloc(3ull * 256 * 1024 * 4);
  u32* BAR = (u32*)alloc(16384);  // barrier/census area (see layout comment)
  if (off > ws_size) return;  // workspace too small: fail loudly (validation)

  const int BIG = 1 << 30;
  // weight repack (one-time per call)
  transpose_bf16<<<dim3(256, 16), 256, 0, stream>>>(W_hh0, nullptr, 4096, BIG, 1024, 4096, 1, WT0, 1024);
  transpose_bf16<<<dim3(256, 32), 256, 0, stream>>>(W_ih1, W_hh1, 4096, 1024, 2048, 4096, 1, WT1, 2048);
  transpose_bf16<<<dim3(256, 32), 256, 0, stream>>>(W_ih2, W_hh2, 4096, 1024, 2048, 4096, 1, WT2, 2048);
  transpose_bf16<<<dim3(256, 4), 256, 0, stream>>>(W_ih0, nullptr, 4096, BIG, 204, 4096, 1, WT00, 256);
  transpose_bf16<<<dim3(16, 16), 256, 0, stream>>>(fc_W, nullptr, 204, BIG, 1024, 204, 0, FCW, 1024);
  transpose_bf16<<<dim3(192, 4), 256, 0, stream>>>(inh_W, nullptr, 3072, BIG, 204, 3072, 0, WIH, 256);
  transpose_bf16<<<dim3(192, 4), 256, 0, stream>>>(inc_W, nullptr, 3072, BIG, 204, 3072, 0, WIC, 256);
  build_frame<<<256, 256, 0, stream>>>(inputs, FRB);
  build_bias<<<16, 256, 0, stream>>>(W_ih0, b_ih0, b_hh0, b_ih1, b_hh1, b_ih2,
                                     b_hh2, labels, G0B, B1P, B2P);
  hipMemsetAsync(BAR, 0, 16384, stream);

  Params p;
  p.fc_b = fc_b; p.inh_b = inh_b; p.inc_b = inc_b;
  p.WT0 = WT0; p.WT1 = WT1; p.WT2 = WT2; p.WT00 = WT00; p.FCW = FCW;
  p.WIH = WIH; p.WIC = WIC; p.FRB = FRB; p.HB = HB;
  p.G0P = G0P; p.G0B = G0B; p.B1P = B1P; p.B2P = B2P; p.CC = CC;
  p.out = (float*)d_out;

  setup_mm<<<160, 512, 0, stream>>>(p);

  // persistent pipelined sequence: one plain launch, software grid barrier
  persist_kernel<<<196, 512, 0, stream>>>(p, BAR);
}

// Round 17
// 5148.026 us; speedup vs baseline: 1.0246x; 1.0246x over previous
//
#include <hip/hip_runtime.h>

// DecoderRNN: 3-layer LSTM (H=1024) + fc, B=256, 128 steps, constant input.
// bf16 MFMA 16x16x32; gate-interleaved weight columns; persistent plain-launch
// kernel. THIS ROUND: dataflow flags instead of global barrier.
// h-state written WRITE-THROUGH (global_store_short sc0 sc1 -> MALL), read
// via sc0|sc1 coherent loads (R8-proven). NO fences, NO wbl2, NO lockstep:
// per-(job,step) done-counters; h triple-buffered for WAR back-pressure.

#define DEVINL static __device__ __forceinline__

typedef __bf16 bf16x8 __attribute__((ext_vector_type(8)));
typedef float f32x4 __attribute__((ext_vector_type(4)));
typedef unsigned short u16;
typedef unsigned int u32;
typedef unsigned long long u64;

DEVINL u16 f2bf(float f) {
  u32 u = __builtin_bit_cast(u32, f);
  u += 0x7fffu + ((u >> 16) & 1u);  // RNE
  return (u16)(u >> 16);
}
DEVINL float bf2f(u16 h) {
  u32 u = (u32)h << 16;
  return __builtin_bit_cast(float, u);
}
DEVINL float sigm(float x) { return 1.0f / (1.0f + __expf(-x)); }
DEVINL float tanhfast(float x) { return 1.0f - 2.0f / (1.0f + __expf(2.0f * x)); }

// device-coherent global->LDS (h-state, reads MALL) [R8-proven]
DEVINL void glds_coh(const u16* g, u16* l) {
  __builtin_amdgcn_global_load_lds(
      (const __attribute__((address_space(1))) u32*)g,
      (__attribute__((address_space(3))) u32*)l, 16, 0, 17);  // sc0|sc1
}
// cached global->LDS (weights: read-only)
DEVINL void glds_w(const u16* g, u16* l) {
  __builtin_amdgcn_global_load_lds(
      (const __attribute__((address_space(1))) u32*)g,
      (__attribute__((address_space(3))) u32*)l, 16, 0, 0);
}
// write-through u16 store (h-state -> MALL; no L2 dirty line, no fence needed)
DEVINL void st_coh_u16(u16* p, u16 v) {
  asm volatile("global_store_short %0, %1, off sc0 sc1" ::"v"(p), "v"((u32)v)
               : "memory");
}

// permuted column index -> original gate column: P = grp*64 + g*16 + jj
DEVINL int permcol(int P) {
  int grp = P >> 6, g = (P >> 4) & 3, jj = P & 15;
  return g * 1024 + grp * 16 + jj;
}

struct Params {
  const float* fc_b;
  const float* inh_b;
  const float* inc_b;
  const u16 *WT0, *WT1, *WT2, *WT00, *FCW, *WIH, *WIC, *FRB;
  u16* HB;   // h state bf16: [layer][3 parities][256][1024] (1<<18 u16/buf)
  u16* G0P;  // precomputed layer0 input gates, bf16 [256][4096]
  float *G0B, *B1P, *B2P, *CC;  // CC: c state fp32 [layer][256][1024]
  float* out;
};

#define MODE_L0 0
#define MODE_L 1
#define MODE_FC 2
#define MODE_G0 3
#define MODE_H 4
#define MODE_C 5

// one 64-K tile: per thread 4 A-loads (coherent) + 2 B-loads (cached),
// direct to LDS. Source-side XOR swizzle (granule ^ row&7); LDS dest linear.
DEVINL void issue_tile(int kt, const u16* A0, const u16* A1, int kSplit, int sA,
                       int K, const u16* Wt, int m0, int wrow,
                       const int (&rq)[4], const int (&kqs)[4],
                       const int (&lo)[4], u16* Abuf, u16* Bbuf) {
  const u16* Ab = (kt < kSplit) ? (A0 + kt) : (A1 + (kt - kSplit));
#pragma unroll
  for (int q = 0; q < 4; ++q)
    glds_coh(Ab + (size_t)(m0 + rq[q]) * sA + kqs[q] * 8, Abuf + lo[q]);
  const u16* Bb = Wt + kt;
#pragma unroll
  for (int q = 0; q < 2; ++q)
    glds_w(Bb + (size_t)(wrow + rq[q]) * K + kqs[q] * 8, Bbuf + lo[q]);
}

DEVINL void mfma_tile(const u16* Al, const u16* Bl, f32x4 (&acc)[2][4], int rl0,
                      int hh, int e7, int jj) {
#pragma unroll
  for (int kk = 0; kk < 2; ++kk) {
    int sl = (((kk << 2) | hh) ^ e7) * 8;
    bf16x8 a0 = *(const bf16x8*)(Al + rl0 * 64 + sl);
    bf16x8 a1 = *(const bf16x8*)(Al + (rl0 + 16) * 64 + sl);
    bf16x8 b0 = *(const bf16x8*)(Bl + (jj)*64 + sl);
    bf16x8 b1 = *(const bf16x8*)(Bl + (16 + jj) * 64 + sl);
    bf16x8 b2 = *(const bf16x8*)(Bl + (32 + jj) * 64 + sl);
    bf16x8 b3 = *(const bf16x8*)(Bl + (48 + jj) * 64 + sl);
    acc[0][0] = __builtin_amdgcn_mfma_f32_16x16x32_bf16(a0, b0, acc[0][0], 0, 0, 0);
    acc[0][1] = __builtin_amdgcn_mfma_f32_16x16x32_bf16(a0, b1, acc[0][1], 0, 0, 0);
    acc[0][2] = __builtin_amdgcn_mfma_f32_16x16x32_bf16(a0, b2, acc[0][2], 0, 0, 0);
    acc[0][3] = __builtin_amdgcn_mfma_f32_16x16x32_bf16(a0, b3, acc[0][3], 0, 0, 0);
    acc[1][0] = __builtin_amdgcn_mfma_f32_16x16x32_bf16(a1, b0, acc[1][0], 0, 0, 0);
    acc[1][1] = __builtin_amdgcn_mfma_f32_16x16x32_bf16(a1, b1, acc[1][1], 0, 0, 0);
    acc[1][2] = __builtin_amdgcn_mfma_f32_16x16x32_bf16(a1, b2, acc[1][2], 0, 0, 0);
    acc[1][3] = __builtin_amdgcn_mfma_f32_16x16x32_bf16(a1, b3, acc[1][3], 0, 0, 0);
  }
}

// Block: 256 threads = 4 waves, output tile 128(M) x 64(N); wave w = rows
// [w*32, w*32+32): 2 M-frags x 4 N-frags. LDS double-buffered.
// Counted vmcnt(6): next tile's 6 loads stay in flight across both barriers.
// COH template flag: h-output stores write-through when 1.
template <int MODE, int COH>
DEVINL void mm_body(u16* Al, u16* Bl, const u16* A0, const u16* A1, int sA,
                    int kSplit, int K, const u16* Wt, int m0, int bn, int t,
                    const u16* Gfull, const float* biasP, float* Cst, u16* Hout,
                    float* outp) {
  const int tid = threadIdx.x;
  const int l = tid & 63;
  const int w = tid >> 6;
  const int hh = (l >> 4) & 3;
  const int jj = l & 15;
  const int rl0 = w * 32 + jj;
  const int e7 = l & 7;

  int rq[4], kqs[4], lo[4];
#pragma unroll
  for (int q = 0; q < 4; ++q) {
    int L = tid + q * 256;
    rq[q] = L >> 3;
    kqs[q] = (L & 7) ^ (rq[q] & 7);       // source-swizzled granule
    lo[q] = ((tid & ~63) + q * 256) * 8;  // wave-uniform LDS base (u16 units)
  }

  f32x4 acc[2][4];
#pragma unroll
  for (int m = 0; m < 2; ++m)
#pragma unroll
    for (int g = 0; g < 4; ++g) acc[m][g] = (f32x4){0.f, 0.f, 0.f, 0.f};

  const int wrow = bn * 64;
  const int n = K >> 6;  // 64-K tiles

  issue_tile(0, A0, A1, kSplit, sA, K, Wt, m0, wrow, rq, kqs, lo, Al, Bl);
  issue_tile(64, A0, A1, kSplit, sA, K, Wt, m0, wrow, rq, kqs, lo, Al + 8192,
             Bl + 4096);

  for (int j = 0; j < n; ++j) {
    u16* Ac = Al + (j & 1) * 8192;
    u16* Bc = Bl + (j & 1) * 4096;
    if (j < n - 1)
      asm volatile("s_waitcnt vmcnt(6)" ::: "memory");
    else
      asm volatile("s_waitcnt vmcnt(0)" ::: "memory");
    __builtin_amdgcn_s_barrier();
    __builtin_amdgcn_sched_barrier(0);
    mfma_tile(Ac, Bc, acc, rl0, hh, e7, jj);
    __builtin_amdgcn_sched_barrier(0);
    __builtin_amdgcn_s_barrier();
    if (j + 2 < n)
      issue_tile((j + 2) * 64, A0, A1, kSplit, sA, K, Wt, m0, wrow, rq, kqs, lo,
                 Ac, Bc);
  }

  // C/D layout: col = lane&15, row = (lane>>4)*4 + reg  [m89-verified]
  const int rb = m0 + w * 32 + (hh << 2);
  if (MODE <= MODE_L) {
    float add0 = 0.f, add1 = 0.f, add2 = 0.f, add3 = 0.f;
    if (MODE == MODE_L) {
      add0 = biasP[bn * 64 + jj];
      add1 = biasP[bn * 64 + 16 + jj];
      add2 = biasP[bn * 64 + 32 + jj];
      add3 = biasP[bn * 64 + 48 + jj];
    }
    const int j = bn * 16 + jj;  // hidden unit
#pragma unroll
    for (int m = 0; m < 2; ++m) {
#pragma unroll
      for (int r = 0; r < 4; ++r) {
        int b = rb + m * 16 + r;
        float g0v, g1v, g2v, g3v;
        if (MODE == MODE_L0) {
          const u16* G = Gfull + (size_t)b * 4096 + bn * 64 + jj;
          g0v = acc[m][0][r] + bf2f(G[0]);
          g1v = acc[m][1][r] + bf2f(G[16]);
          g2v = acc[m][2][r] + bf2f(G[32]);
          g3v = acc[m][3][r] + bf2f(G[48]);
        } else {
          g0v = acc[m][0][r] + add0;
          g1v = acc[m][1][r] + add1;
          g2v = acc[m][2][r] + add2;
          g3v = acc[m][3][r] + add3;
        }
        float iv = sigm(g0v), fv = sigm(g1v), gv = tanhfast(g2v), ov = sigm(g3v);
        size_t ci = (size_t)b * 1024 + j;
        float cn = fv * Cst[ci] + iv * gv;
        Cst[ci] = cn;
        u16 hv = f2bf(ov * tanhfast(cn));
        if (COH)
          st_coh_u16(Hout + ci, hv);  // write-through to MALL
        else
          Hout[ci] = hv;
      }
    }
  } else if (MODE == MODE_FC) {
#pragma unroll
    for (int g = 0; g < 4; ++g) {
      int nn = bn * 64 + g * 16 + jj;
      if (nn < 204) {
        float bv2 = biasP[nn];
#pragma unroll
        for (int m = 0; m < 2; ++m)
#pragma unroll
          for (int r = 0; r < 4; ++r) {
            int b = rb + m * 16 + r;
            outp[((size_t)b * 128 + t) * 204 + nn] = acc[m][g][r] + bv2;
          }
      }
    }
  } else if (MODE == MODE_G0) {
#pragma unroll
    for (int g = 0; g < 4; ++g) {
      int P = bn * 64 + g * 16 + jj;
      float bv2 = biasP[P];
#pragma unroll
      for (int m = 0; m < 2; ++m)
#pragma unroll
        for (int r = 0; r < 4; ++r) {
          int b = rb + m * 16 + r;
          Hout[(size_t)b * 4096 + P] = f2bf(acc[m][g][r] + bv2);
        }
    }
  } else {  // MODE_H / MODE_C : init states, cols are orig n = lay*1024 + j
#pragma unroll
    for (int g = 0; g < 4; ++g) {
      int nn = bn * 64 + g * 16 + jj;
      int lay = nn >> 10, j2 = nn & 1023;
      float bv2 = biasP[nn];
#pragma unroll
      for (int m = 0; m < 2; ++m)
#pragma unroll
        for (int r = 0; r < 4; ++r) {
          int b = rb + m * 16 + r;
          float v = acc[m][g][r] + bv2;
          if (MODE == MODE_H)  // init h -> parity 2 of each layer
            Hout[(size_t)((lay * 3 + 2) * 256 + b) * 1024 + j2] = f2bf(v);
          else
            outp[(size_t)(lay * 256 + b) * 1024 + j2] = v;
        }
    }
  }
}

// done[j][t] counters: bar + (j*128 + t)*16  (64B apart). Poll helper.
DEVINL void wait_cnt(u32* c, u32 target) {
#pragma unroll 1
  while (__hip_atomic_load(c, __ATOMIC_RELAXED, __HIP_MEMORY_SCOPE_AGENT) <
         target)
    __builtin_amdgcn_s_sleep(4);
}

// Persistent dataflow kernel, PLAIN launch; 392 blocks co-resident:
// LDS 48KB -> 3 blocks/CU; launch_bounds(256,2) -> VGPR<=128; 392 <= 512.
// jobs 0..2: 128 blocks (64 bn x 2 M-halves); fc: 8.
// Deps per step t: job j waits done[j-1][t] (producer), done[j][t-1] (full
// own-layer h), done[j+1][t-3] (WAR back-pressure; h triple-buffered).
__global__ __launch_bounds__(256, 2) void persist_kernel(Params p, u32* bar) {
  __shared__ u16 Al[2 * 128 * 64];  // 32KB
  __shared__ u16 Bl[2 * 64 * 64];   // 16KB
  const int bid = blockIdx.x;
  int job, mb, bn;
  if (bid < 384) {
    job = bid >> 7;
    int r = bid & 127;
    bn = (r & 7) * 8 + (r >> 4);  // bn>>3 == bid&7 (XCD-affine weight slice)
    mb = (r >> 3) & 1;
  } else {
    job = 3;
    int r = bid - 384;
    mb = r >> 2;
    bn = r & 3;
  }
  u16* HB = p.HB;
#define HBP(lay, pp) (HB + (size_t)(((lay)*3 + (pp)) << 18))
#define D(j, tt) (bar + ((j)*128 + (tt)) * 16)
  for (int t = 0; t < 128; ++t) {
    if (threadIdx.x == 0) {
      if (job == 0) {
        if (t >= 1) wait_cnt(D(0, t - 1), 128u);
        if (t >= 3) wait_cnt(D(1, t - 3), 128u);
      } else if (job == 1) {
        wait_cnt(D(0, t), 128u);
        if (t >= 1) wait_cnt(D(1, t - 1), 128u);
        if (t >= 3) wait_cnt(D(2, t - 3), 128u);
      } else if (job == 2) {
        wait_cnt(D(1, t), 128u);
        if (t >= 1) wait_cnt(D(2, t - 1), 128u);
        if (t >= 3) wait_cnt(D(3, t - 3), 8u);
      } else {
        wait_cnt(D(2, t), 128u);
      }
    }
    __syncthreads();  // inputs ready for all waves
    int par = t % 3, pv = (t + 2) % 3;
    if (job == 0) {
      mm_body<MODE_L0, 1>(Al, Bl, HBP(0, pv), nullptr, 1024, 1 << 30, 1024,
                          p.WT0, mb * 128, bn, t, p.G0P, nullptr, p.CC,
                          HBP(0, par), nullptr);
    } else if (job == 1) {
      mm_body<MODE_L, 1>(Al, Bl, HBP(0, par), HBP(1, pv), 1024, 1024, 2048,
                         p.WT1, mb * 128, bn, t, nullptr, p.B1P,
                         p.CC + (size_t)256 * 1024, HBP(1, par), nullptr);
    } else if (job == 2) {
      mm_body<MODE_L, 1>(Al, Bl, HBP(1, par), HBP(2, pv), 1024, 1024, 2048,
                         p.WT2, mb * 128, bn, t, nullptr, p.B2P,
                         p.CC + (size_t)512 * 1024, HBP(2, par), nullptr);
    } else {
      mm_body<MODE_FC, 0>(Al, Bl, HBP(2, par), nullptr, 1024, 1 << 30, 1024,
                          p.FCW, mb * 128, bn, t, nullptr, p.fc_b, nullptr,
                          nullptr, p.out);
    }
    __syncthreads();  // all waves' stores drained (vmcnt0 before s_barrier)
    if (threadIdx.x == 0)
      __hip_atomic_fetch_add(D(job, t), 1u, __ATOMIC_RELAXED,
                             __HIP_MEMORY_SCOPE_AGENT);
  }
#undef D
#undef HBP
}

// one-time: G0 = x_in@W_ih0+biases (permuted), h/c init = frame@in{h,c}_W + b
__global__ __launch_bounds__(256, 2) void setup_mm(Params p) {
  __shared__ u16 Al[2 * 128 * 64];
  __shared__ u16 Bl[2 * 64 * 64];
  int bid = blockIdx.x;
  if (bid < 128) {
    mm_body<MODE_G0, 0>(Al, Bl, p.FRB, nullptr, 256, 1 << 30, 256, p.WT00,
                        (bid >> 6) * 128, bid & 63, 0, nullptr, p.G0B, nullptr,
                        p.G0P, nullptr);
  } else if (bid < 224) {
    int b2 = bid - 128;
    mm_body<MODE_H, 0>(Al, Bl, p.FRB, nullptr, 256, 1 << 30, 256, p.WIH,
                       (b2 / 48) * 128, b2 % 48, 0, nullptr, p.inh_b, nullptr,
                       p.HB, nullptr);
  } else {
    int b2 = bid - 224;
    mm_body<MODE_C, 0>(Al, Bl, p.FRB, nullptr, 256, 1 << 30, 256, p.WIC,
                       (b2 / 48) * 128, b2 % 48, 0, nullptr, p.inc_b, nullptr,
                       nullptr, p.CC);
  }
}

// fp32 [K][N] sources -> bf16 transposed dst [Nout][Ktot] (K contiguous),
// optional gate permutation of output cols, zero pad k>=Kvalid / n>=Nvalid.
__global__ __launch_bounds__(256) void transpose_bf16(
    const float* __restrict__ srcA, const float* __restrict__ srcB,
    int srcStride, int kSplit, int Kvalid, int Nvalid, int perm,
    u16* __restrict__ dst, int Ktot) {
  __shared__ float tile[64][17];
  int P0 = blockIdx.x * 16;
  int k0 = blockIdx.y * 64;
  int t = threadIdx.x;
  int nl = t & 15;
  int kh = t >> 4;
  int P = P0 + nl;
  int n = perm ? permcol(P) : P;
  bool nok = (n < Nvalid);
#pragma unroll
  for (int q = 0; q < 4; ++q) {
    int kl = q * 16 + kh;
    int k = k0 + kl;
    float v = 0.f;
    if (nok && k < Kvalid) {
      const float* s = (k < kSplit) ? (srcA + (size_t)k * srcStride)
                                    : (srcB + (size_t)(k - kSplit) * srcStride);
      v = s[n];
    }
    tile[kl][nl] = v;
  }
  __syncthreads();
  int jo = t >> 4;
  int kb = (t & 15) << 2;
  u64 pk = (u64)f2bf(tile[kb + 0][jo]) | ((u64)f2bf(tile[kb + 1][jo]) << 16) |
           ((u64)f2bf(tile[kb + 2][jo]) << 32) |
           ((u64)f2bf(tile[kb + 3][jo]) << 48);
  *(u64*)(dst + (size_t)(P0 + jo) * Ktot + k0 + kb) = pk;
}

__global__ __launch_bounds__(256) void build_frame(const float* __restrict__ inputs,
                                                   u16* __restrict__ FRB) {
  int id = blockIdx.x * 256 + threadIdx.x;  // 256*256
  int b = id >> 8, k = id & 255;
  FRB[id] = (k < 204) ? f2bf(inputs[b * 204 + k]) : (u16)0;
}

// G0 bias incl. one-hot label row; layer1/2 combined biases (permuted cols)
__global__ __launch_bounds__(256) void build_bias(
    const float* __restrict__ W_ih0, const float* __restrict__ b_ih0,
    const float* __restrict__ b_hh0, const float* __restrict__ b_ih1,
    const float* __restrict__ b_hh1, const float* __restrict__ b_ih2,
    const float* __restrict__ b_hh2, const int* __restrict__ labels,
    float* __restrict__ G0B, float* __restrict__ B1P, float* __restrict__ B2P) {
  int P = blockIdx.x * 256 + threadIdx.x;  // 4096
  int n = permcol(P);
  int lab = labels[0];
  G0B[P] = W_ih0[(size_t)(204 + lab) * 4096 + n] + b_ih0[n] + b_hh0[n];
  B1P[P] = b_ih1[n] + b_hh1[n];
  B2P[P] = b_ih2[n] + b_hh2[n];
}

extern "C" void kernel_launch(void* const* d_in, const int* in_sizes, int n_in,
                              void* d_out, int out_size, void* d_ws,
                              size_t ws_size, hipStream_t stream) {
  const float* inputs = (const float*)d_in[0];
  const float* W_ih0 = (const float*)d_in[1];
  const float* W_hh0 = (const float*)d_in[2];
  const float* b_ih0 = (const float*)d_in[3];
  const float* b_hh0 = (const float*)d_in[4];
  const float* W_ih1 = (const float*)d_in[5];
  const float* W_hh1 = (const float*)d_in[6];
  const float* b_ih1 = (const float*)d_in[7];
  const float* b_hh1 = (const float*)d_in[8];
  const float* W_ih2 = (const float*)d_in[9];
  const float* W_hh2 = (const float*)d_in[10];
  const float* b_ih2 = (const float*)d_in[11];
  const float* b_hh2 = (const float*)d_in[12];
  const float* fc_W = (const float*)d_in[13];
  const float* fc_b = (const float*)d_in[14];
  const float* inh_W = (const float*)d_in[15];
  const float* inh_b = (const float*)d_in[16];
  const float* inc_W = (const float*)d_in[17];
  const float* inc_b = (const float*)d_in[18];
  const int* labels = (const int*)d_in[19];

  char* ws = (char*)d_ws;
  size_t off = 0;
  auto alloc = [&](size_t bytes) {
    void* r = ws + off;
    off = (off + bytes + 255) & ~(size_t)255;
    return r;
  };
  u16* WT0 = (u16*)alloc(4096ull * 1024 * 2);
  u16* WT1 = (u16*)alloc(4096ull * 2048 * 2);
  u16* WT2 = (u16*)alloc(4096ull * 2048 * 2);
  u16* WT00 = (u16*)alloc(4096ull * 256 * 2);
  u16* FCW = (u16*)alloc(256ull * 1024 * 2);
  u16* WIH = (u16*)alloc(3072ull * 256 * 2);
  u16* WIC = (u16*)alloc(3072ull * 256 * 2);
  u16* FRB = (u16*)alloc(256ull * 256 * 2);
  u16* HB = (u16*)alloc(3ull * 3 * 256 * 1024 * 2);  // 3 layers x 3 parities
  u16* G0P = (u16*)alloc(256ull * 4096 * 2);
  float* G0B = (float*)alloc(4096ull * 4);
  float* B1P = (float*)alloc(4096ull * 4);
  float* B2P = (float*)alloc(4096ull * 4);
  float* CC = (float*)alloc(3ull * 256 * 1024 * 4);
  u32* BAR = (u32*)alloc(40960);  // done[4][128] counters, 64B apart
  if (off > ws_size) return;  // workspace too small: fail loudly (validation)

  const int BIG = 1 << 30;
  // weight repack (one-time per call)
  transpose_bf16<<<dim3(256, 16), 256, 0, stream>>>(W_hh0, nullptr, 4096, BIG, 1024, 4096, 1, WT0, 1024);
  transpose_bf16<<<dim3(256, 32), 256, 0, stream>>>(W_ih1, W_hh1, 4096, 1024, 2048, 4096, 1, WT1, 2048);
  transpose_bf16<<<dim3(256, 32), 256, 0, stream>>>(W_ih2, W_hh2, 4096, 1024, 2048, 4096, 1, WT2, 2048);
  transpose_bf16<<<dim3(256, 4), 256, 0, stream>>>(W_ih0, nullptr, 4096, BIG, 204, 4096, 1, WT00, 256);
  transpose_bf16<<<dim3(16, 16), 256, 0, stream>>>(fc_W, nullptr, 204, BIG, 1024, 204, 0, FCW, 1024);
  transpose_bf16<<<dim3(192, 4), 256, 0, stream>>>(inh_W, nullptr, 3072, BIG, 204, 3072, 0, WIH, 256);
  transpose_bf16<<<dim3(192, 4), 256, 0, stream>>>(inc_W, nullptr, 3072, BIG, 204, 3072, 0, WIC, 256);
  build_frame<<<256, 256, 0, stream>>>(inputs, FRB);
  build_bias<<<16, 256, 0, stream>>>(W_ih0, b_ih0, b_hh0, b_ih1, b_hh1, b_ih2,
                                     b_hh2, labels, G0B, B1P, B2P);
  hipMemsetAsync(BAR, 0, 40960, stream);

  Params p;
  p.fc_b = fc_b; p.inh_b = inh_b; p.inc_b = inc_b;
  p.WT0 = WT0; p.WT1 = WT1; p.WT2 = WT2; p.WT00 = WT00; p.FCW = FCW;
  p.WIH = WIH; p.WIC = WIC; p.FRB = FRB; p.HB = HB;
  p.G0P = G0P; p.G0B = G0B; p.B1P = B1P; p.B2P = B2P; p.CC = CC;
  p.out = (float*)d_out;

  setup_mm<<<320, 256, 0, stream>>>(p);

  // persistent dataflow sequence: one plain launch, per-(job,step) flags
  persist_kernel<<<392, 256, 0, stream>>>(p, BAR);
}